// Round 17
// baseline (61.005 us; speedup 1.0000x reference)
//
#include <hip/hip_runtime.h>
#include <math.h>

#define HID 1024
#define SEQ 4096
#define NB 16
#define CHUNK 128
#define NCHUNK (SEQ / CHUNK)   // 32 chunks per batch

typedef float floatx4 __attribute__((ext_vector_type(4)));

// ---------------------------------------------------------------------------
// Kernel A1: tiled fp64 partial GEMV over 32h x 64j tiles of Wp.
// grid (32 hsegs, 16 jsegs), block 256 (wave = 4 batches x 64 j).
// Wp read exactly once (4 MB), coalesced; validated R9-R16.
// ---------------------------------------------------------------------------
__global__ __launch_bounds__(256) void kA1(const float* __restrict__ tgt,
                                           const float* __restrict__ Wp,
                                           double* __restrict__ hPart) {
  __shared__ float tls[NB][32];
  const int hseg = blockIdx.x;           // 0..31
  const int jseg = blockIdx.y;           // 0..15
  const int h0 = hseg * 32, j0 = jseg * 64;
  const int tid = threadIdx.x;

  for (int i = tid; i < NB * 32; i += 256)
    tls[i >> 5][i & 31] = tgt[(i >> 5) * HID + h0 + (i & 31)];
  __syncthreads();

  const int jl = tid & 63;               // j lane
  const int bg = tid >> 6;               // batch group (4 batches)
  double a0 = 0.0, a1 = 0.0, a2 = 0.0, a3 = 0.0;
  const float* wp = Wp + (size_t)h0 * HID + j0 + jl;
  #pragma unroll 8
  for (int hh = 0; hh < 32; ++hh) {
    const double w = (double)wp[(size_t)hh * HID];
    a0 += (double)tls[bg * 4 + 0][hh] * w;
    a1 += (double)tls[bg * 4 + 1][hh] * w;
    a2 += (double)tls[bg * 4 + 2][hh] * w;
    a3 += (double)tls[bg * 4 + 3][hh] * w;
  }
  double* hp = hPart + (((size_t)hseg * NB) << 10) + j0 + jl;
  hp[(size_t)(bg * 4 + 0) << 10] = a0;
  hp[(size_t)(bg * 4 + 1) << 10] = a1;
  hp[(size_t)(bg * 4 + 2) << 10] = a2;
  hp[(size_t)(bg * 4 + 3) << 10] = a3;
}

// ---------------------------------------------------------------------------
// Kernel A2: fold 32 hseg partials, tanh, dot v_p within jseg.
// grid (16 batches, 16 jsegs), block 64.
// ---------------------------------------------------------------------------
__global__ __launch_bounds__(64) void kA2(const double* __restrict__ hPart,
                                          const float* __restrict__ bp,
                                          const float* __restrict__ vp,
                                          double* __restrict__ jsegPart) {
  const int b = blockIdx.x, jseg = blockIdx.y;
  const int j = jseg * 64 + threadIdx.x;
  double s = 0.0;
  #pragma unroll 8
  for (int hs = 0; hs < 32; ++hs)
    s += hPart[(((size_t)hs * NB + b) << 10) + j];
  double val = tanh(s + (double)bp[j]) * (double)vp[j];
  #pragma unroll
  for (int off = 32; off; off >>= 1) val += __shfl_xor(val, off);
  if (threadIdx.x == 0) jsegPart[b * 16 + jseg] = val;
}

// ---------------------------------------------------------------------------
// Kernel B: fused score+exp+gauss+context partial.
// CHUNK=128, block 512 (8 waves x 16 rows), grid 512 = 2 blocks/CU
// -> 16 waves/CU = 4 waves/SIMD (was 2: block geometry bound it, and the
// phase-aligned dot+reduce bubbles could not be hidden — the R12/R14/R16
// null results all point here). 2-deep dbuf (depth-3 was null), ~110 VGPR
// keeps 4 waves/SIMD legal (<128 cliff). NO min-waves hint (R6 lesson).
// ---------------------------------------------------------------------------
__device__ __forceinline__ float4 nt_load4(const float* p) {
  floatx4 v = __builtin_nontemporal_load((const floatx4*)p);
  return make_float4(v.x, v.y, v.z, v.w);
}

__global__ __launch_bounds__(512) void kB(const float* __restrict__ src,
                                          const float* __restrict__ tgt,
                                          const double* __restrict__ jsegPart,
                                          const float* __restrict__ bv,
                                          float* __restrict__ zPart,
                                          float* __restrict__ ctxPart) {
  const int chunk = blockIdx.x;      // 0..511
  const int b = chunk >> 5;
  const int c = chunk & 31;
  const int s0 = c * CHUNK;
  const int tid = threadIdx.x;
  const int wave = tid >> 6;         // 0..7
  const int lane = tid & 63;

  // finalize p for this batch (deterministic fp64 sum of 16 partials)
  double lg = (double)bv[0];
  const double* jp = jsegPart + b * 16;
  #pragma unroll
  for (int i = 0; i < 16; ++i) lg += jp[i];
  const float pb = (float)(4096.0 / (1.0 + exp(-lg)));

  // target fragment (16 floats per lane), pre-scaled by 1/sqrt(H)
  float4 tf[4];
  const float4* tg4 = (const float4*)(tgt + b * HID);
  #pragma unroll
  for (int k = 0; k < 4; ++k) {
    tf[k] = tg4[k * 64 + lane];
    tf[k].x *= 0.03125f; tf[k].y *= 0.03125f;
    tf[k].z *= 0.03125f; tf[k].w *= 0.03125f;
  }

  float4 acc[4];
  #pragma unroll
  for (int k = 0; k < 4; ++k) acc[k] = make_float4(0.f, 0.f, 0.f, 0.f);
  float z = 0.f;

  const int srow0 = s0 + wave * 16;          // 16 rows per wave
  const float ds0 = (float)srow0 - pb;
  const float* base = src + ((size_t)b * SEQ + srow0) * HID;

  float4 x[2][4];
  #pragma unroll
  for (int k = 0; k < 4; ++k) x[0][k] = nt_load4(base + (k * 64 + lane) * 4);

  #pragma unroll
  for (int r = 0; r < 16; ++r) {
    const int cur = r & 1, nxt = cur ^ 1;
    if (r + 1 < 16) {
      #pragma unroll
      for (int k = 0; k < 4; ++k)
        x[nxt][k] = nt_load4(base + ((r + 1) * 256 + k * 64 + lane) * 4);
    }

    float dot = 0.f;
    #pragma unroll
    for (int k = 0; k < 4; ++k) {
      dot = fmaf(x[cur][k].x, tf[k].x, dot);
      dot = fmaf(x[cur][k].y, tf[k].y, dot);
      dot = fmaf(x[cur][k].z, tf[k].z, dot);
      dot = fmaf(x[cur][k].w, tf[k].w, dot);
    }
    #pragma unroll
    for (int off = 32; off; off >>= 1) dot += __shfl_xor(dot, off);

    const float w = __expf(dot);                          // dot already scaled
    const float ds = ds0 + (float)r;
    const float g = __expf(ds * ds * (-1.0f / 2048.0f));  // gaussian window
    z += w;
    const float wg = w * g;
    #pragma unroll
    for (int k = 0; k < 4; ++k) {
      acc[k].x = fmaf(wg, x[cur][k].x, acc[k].x);
      acc[k].y = fmaf(wg, x[cur][k].y, acc[k].y);
      acc[k].z = fmaf(wg, x[cur][k].z, acc[k].z);
      acc[k].w = fmaf(wg, x[cur][k].w, acc[k].w);
    }
  }

  // combine 8 waves via LDS
  __shared__ float lctx[8][HID];
  __shared__ float lz[8];
  #pragma unroll
  for (int k = 0; k < 4; ++k)
    *(float4*)&lctx[wave][k * 256 + lane * 4] = acc[k];
  if (lane == 0) lz[wave] = z;
  __syncthreads();

  if (tid < 256) {
    float4 s4 = make_float4(0.f, 0.f, 0.f, 0.f);
    #pragma unroll
    for (int w2 = 0; w2 < 8; ++w2) {
      float4 v = *(const float4*)&lctx[w2][tid * 4];
      s4.x += v.x; s4.y += v.y; s4.z += v.z; s4.w += v.w;
    }
    ((float4*)ctxPart)[(size_t)chunk * 256 + tid] = s4;
    if (tid == 0) {
      float zs = 0.f;
      #pragma unroll
      for (int w2 = 0; w2 < 8; ++w2) zs += lz[w2];
      zPart[chunk] = zs;
    }
  }
}

// ---------------------------------------------------------------------------
// Kernel C: combine 32 chunk partials per batch, divide by Z.
// grid (16 batches, 16 hsegs), block 256 (4 chunk-groups x 64 cols).
// ---------------------------------------------------------------------------
__global__ __launch_bounds__(256) void kC(const float* __restrict__ zPart,
                                          const float* __restrict__ ctxPart,
                                          float* __restrict__ out) {
  __shared__ float red[4][64];
  const int b = blockIdx.x;
  const int hseg = blockIdx.y;
  const int tid = threadIdx.x;
  const int col = tid & 63;
  const int grp = tid >> 6;

  float acc = 0.f;
  #pragma unroll
  for (int i = 0; i < 8; ++i) {
    const int chunk = grp * 8 + i;     // 4 groups x 8 = 32 chunks
    acc += ctxPart[((size_t)(b * NCHUNK + chunk)) * HID + hseg * 64 + col];
  }
  red[grp][col] = acc;
  __syncthreads();

  if (tid < 64) {
    float zv = zPart[b * NCHUNK + (tid & 31)];   // 32 values, halves mirror
    #pragma unroll
    for (int off = 16; off; off >>= 1) zv += __shfl_xor(zv, off);
    const float s = red[0][tid] + red[1][tid] + red[2][tid] + red[3][tid];
    out[b * HID + hseg * 64 + tid] = s / zv;
  }
}

// ---------------------------------------------------------------------------
extern "C" void kernel_launch(void* const* d_in, const int* in_sizes, int n_in,
                              void* d_out, int out_size, void* d_ws, size_t ws_size,
                              hipStream_t stream) {
  const float* src = (const float*)d_in[0];   // (16, 4096, 1024)
  const float* tgt = (const float*)d_in[1];   // (16, 1024)
  const float* Wp  = (const float*)d_in[2];   // (1024, 1024)
  const float* bp  = (const float*)d_in[3];   // (1024,)
  const float* vp  = (const float*)d_in[4];   // (1024,)
  const float* bv  = (const float*)d_in[5];   // scalar
  float* out = (float*)d_out;

  // ws layout (every region fully rewritten before use each call)
  double* hPart    = (double*)d_ws;                            // 4 MB
  double* jsegPart = (double*)((char*)d_ws + (4 << 20));       // 2 KB
  float*  zPart    = (float*)((char*)d_ws + (4 << 20) + 8192); // 2 KB
  float*  ctxPart  = (float*)((char*)d_ws + (5 << 20));        // 2 MB

  kA1<<<dim3(32, 16), 256, 0, stream>>>(tgt, Wp, hPart);
  kA2<<<dim3(NB, 16), 64, 0, stream>>>(hPart, bp, vp, jsegPart);
  kB<<<NB * NCHUNK, 512, 0, stream>>>(src, tgt, jsegPart, bv, zPart, ctxPart);
  kC<<<dim3(NB, 16), 256, 0, stream>>>(zPart, ctxPart, out);
}

// Round 18
// 58.355 us; speedup vs baseline: 1.0454x; 1.0454x over previous
//
#include <hip/hip_runtime.h>
#include <math.h>

#define HID 1024
#define SEQ 4096
#define NB 16
#define CHUNK 256
#define NCHUNK (SEQ / CHUNK)   // 16 chunks per batch

typedef float floatx4 __attribute__((ext_vector_type(4)));

// ---------------------------------------------------------------------------
// Kernel A1: tiled fp64 partial GEMV over 32h x 64j tiles of Wp.
// grid (32 hsegs, 16 jsegs), block 256 (wave = 4 batches x 64 j).
// Wp read exactly once (4 MB), coalesced; validated R9-R16.
// ---------------------------------------------------------------------------
__global__ __launch_bounds__(256) void kA1(const float* __restrict__ tgt,
                                           const float* __restrict__ Wp,
                                           double* __restrict__ hPart) {
  __shared__ float tls[NB][32];
  const int hseg = blockIdx.x;           // 0..31
  const int jseg = blockIdx.y;           // 0..15
  const int h0 = hseg * 32, j0 = jseg * 64;
  const int tid = threadIdx.x;

  for (int i = tid; i < NB * 32; i += 256)
    tls[i >> 5][i & 31] = tgt[(i >> 5) * HID + h0 + (i & 31)];
  __syncthreads();

  const int jl = tid & 63;               // j lane
  const int bg = tid >> 6;               // batch group (4 batches)
  double a0 = 0.0, a1 = 0.0, a2 = 0.0, a3 = 0.0;
  const float* wp = Wp + (size_t)h0 * HID + j0 + jl;
  #pragma unroll 8
  for (int hh = 0; hh < 32; ++hh) {
    const double w = (double)wp[(size_t)hh * HID];
    a0 += (double)tls[bg * 4 + 0][hh] * w;
    a1 += (double)tls[bg * 4 + 1][hh] * w;
    a2 += (double)tls[bg * 4 + 2][hh] * w;
    a3 += (double)tls[bg * 4 + 3][hh] * w;
  }
  double* hp = hPart + (((size_t)hseg * NB) << 10) + j0 + jl;
  hp[(size_t)(bg * 4 + 0) << 10] = a0;
  hp[(size_t)(bg * 4 + 1) << 10] = a1;
  hp[(size_t)(bg * 4 + 2) << 10] = a2;
  hp[(size_t)(bg * 4 + 3) << 10] = a3;
}

// ---------------------------------------------------------------------------
// Kernel A2: fold 32 hseg partials, tanh, dot v_p within jseg.
// grid (16 batches, 16 jsegs), block 64.
// ---------------------------------------------------------------------------
__global__ __launch_bounds__(64) void kA2(const double* __restrict__ hPart,
                                          const float* __restrict__ bp,
                                          const float* __restrict__ vp,
                                          double* __restrict__ jsegPart) {
  const int b = blockIdx.x, jseg = blockIdx.y;
  const int j = jseg * 64 + threadIdx.x;
  double s = 0.0;
  #pragma unroll 8
  for (int hs = 0; hs < 32; ++hs)
    s += hPart[(((size_t)hs * NB + b) << 10) + j];
  double val = tanh(s + (double)bp[j]) * (double)vp[j];
  #pragma unroll
  for (int off = 32; off; off >>= 1) val += __shfl_xor(val, off);
  if (threadIdx.x == 0) jsegPart[b * 16 + jseg] = val;
}

// ---------------------------------------------------------------------------
// Kernel B: fused score+exp+gauss+context partial.
// BEST CONFIG (R16, 58.4 us): CHUNK=256, block 512 (8 waves x 32 rows),
// grid 256 = 1 block/CU, 3-deep rotating row prefetch, NT loads, shfl_xor
// reduce, __expf, prescaled tf. R17's 2-blocks/CU variant regressed (61.0);
// reverted. NO min-waves hint (R6 spill lesson).
// ---------------------------------------------------------------------------
__device__ __forceinline__ float4 nt_load4(const float* p) {
  floatx4 v = __builtin_nontemporal_load((const floatx4*)p);
  return make_float4(v.x, v.y, v.z, v.w);
}

__global__ __launch_bounds__(512) void kB(const float* __restrict__ src,
                                          const float* __restrict__ tgt,
                                          const double* __restrict__ jsegPart,
                                          const float* __restrict__ bv,
                                          float* __restrict__ zPart,
                                          float* __restrict__ ctxPart) {
  const int chunk = blockIdx.x;      // 0..255
  const int b = chunk >> 4;
  const int c = chunk & 15;
  const int s0 = c * CHUNK;
  const int tid = threadIdx.x;
  const int wave = tid >> 6;         // 0..7
  const int lane = tid & 63;

  // finalize p for this batch (deterministic fp64 sum of 16 partials)
  double lg = (double)bv[0];
  const double* jp = jsegPart + b * 16;
  #pragma unroll
  for (int i = 0; i < 16; ++i) lg += jp[i];
  const float pb = (float)(4096.0 / (1.0 + exp(-lg)));

  // target fragment (16 floats per lane), pre-scaled by 1/sqrt(H)
  float4 tf[4];
  const float4* tg4 = (const float4*)(tgt + b * HID);
  #pragma unroll
  for (int k = 0; k < 4; ++k) {
    tf[k] = tg4[k * 64 + lane];
    tf[k].x *= 0.03125f; tf[k].y *= 0.03125f;
    tf[k].z *= 0.03125f; tf[k].w *= 0.03125f;
  }

  float4 acc[4];
  #pragma unroll
  for (int k = 0; k < 4; ++k) acc[k] = make_float4(0.f, 0.f, 0.f, 0.f);
  float z = 0.f;

  const int srow0 = s0 + wave * 32;          // 32 rows per wave
  const float ds0 = (float)srow0 - pb;
  const float* base = src + ((size_t)b * SEQ + srow0) * HID;

  float4 x[3][4];                            // 3-deep rotating row buffer
  #pragma unroll
  for (int k = 0; k < 4; ++k) {
    x[0][k] = nt_load4(base + (k * 64 + lane) * 4);
    x[1][k] = nt_load4(base + (256 + k * 64 + lane) * 4);
  }

  #pragma unroll
  for (int r = 0; r < 32; ++r) {
    const int cur = r % 3;
    if (r + 2 < 32) {
      const int pf = (r + 2) % 3;
      #pragma unroll
      for (int k = 0; k < 4; ++k)
        x[pf][k] = nt_load4(base + ((r + 2) * 256 + k * 64 + lane) * 4);
    }

    float dot = 0.f;
    #pragma unroll
    for (int k = 0; k < 4; ++k) {
      dot = fmaf(x[cur][k].x, tf[k].x, dot);
      dot = fmaf(x[cur][k].y, tf[k].y, dot);
      dot = fmaf(x[cur][k].z, tf[k].z, dot);
      dot = fmaf(x[cur][k].w, tf[k].w, dot);
    }
    #pragma unroll
    for (int off = 32; off; off >>= 1) dot += __shfl_xor(dot, off);

    const float w = __expf(dot);                          // dot already scaled
    const float ds = ds0 + (float)r;
    const float g = __expf(ds * ds * (-1.0f / 2048.0f));  // gaussian window
    z += w;
    const float wg = w * g;
    #pragma unroll
    for (int k = 0; k < 4; ++k) {
      acc[k].x = fmaf(wg, x[cur][k].x, acc[k].x);
      acc[k].y = fmaf(wg, x[cur][k].y, acc[k].y);
      acc[k].z = fmaf(wg, x[cur][k].z, acc[k].z);
      acc[k].w = fmaf(wg, x[cur][k].w, acc[k].w);
    }
  }

  // combine 8 waves via LDS
  __shared__ float lctx[8][HID];
  __shared__ float lz[8];
  #pragma unroll
  for (int k = 0; k < 4; ++k)
    *(float4*)&lctx[wave][k * 256 + lane * 4] = acc[k];
  if (lane == 0) lz[wave] = z;
  __syncthreads();

  if (tid < 256) {
    float4 s4 = make_float4(0.f, 0.f, 0.f, 0.f);
    #pragma unroll
    for (int w2 = 0; w2 < 8; ++w2) {
      float4 v = *(const float4*)&lctx[w2][tid * 4];
      s4.x += v.x; s4.y += v.y; s4.z += v.z; s4.w += v.w;
    }
    ((float4*)ctxPart)[(size_t)chunk * 256 + tid] = s4;
    if (tid == 0) {
      float zs = 0.f;
      #pragma unroll
      for (int w2 = 0; w2 < 8; ++w2) zs += lz[w2];
      zPart[chunk] = zs;
    }
  }
}

// ---------------------------------------------------------------------------
// Kernel C: combine 16 chunk partials per batch, divide by Z.
// grid (16 batches, 16 hsegs), block 256 (4 chunk-groups x 64 cols).
// ---------------------------------------------------------------------------
__global__ __launch_bounds__(256) void kC(const float* __restrict__ zPart,
                                          const float* __restrict__ ctxPart,
                                          float* __restrict__ out) {
  __shared__ float red[4][64];
  const int b = blockIdx.x;
  const int hseg = blockIdx.y;
  const int tid = threadIdx.x;
  const int col = tid & 63;
  const int grp = tid >> 6;

  float acc = 0.f;
  #pragma unroll
  for (int i = 0; i < 4; ++i) {
    const int chunk = grp * 4 + i;     // 4 groups x 4 = 16 chunks
    acc += ctxPart[((size_t)(b * NCHUNK + chunk)) * HID + hseg * 64 + col];
  }
  red[grp][col] = acc;
  __syncthreads();

  if (tid < 64) {
    float zv = zPart[b * NCHUNK + (tid & 15)];   // 16 values, replicated x4
    #pragma unroll
    for (int off = 8; off; off >>= 1) zv += __shfl_xor(zv, off);
    const float s = red[0][tid] + red[1][tid] + red[2][tid] + red[3][tid];
    out[b * HID + hseg * 64 + tid] = s / zv;
  }
}

// ---------------------------------------------------------------------------
extern "C" void kernel_launch(void* const* d_in, const int* in_sizes, int n_in,
                              void* d_out, int out_size, void* d_ws, size_t ws_size,
                              hipStream_t stream) {
  const float* src = (const float*)d_in[0];   // (16, 4096, 1024)
  const float* tgt = (const float*)d_in[1];   // (16, 1024)
  const float* Wp  = (const float*)d_in[2];   // (1024, 1024)
  const float* bp  = (const float*)d_in[3];   // (1024,)
  const float* vp  = (const float*)d_in[4];   // (1024,)
  const float* bv  = (const float*)d_in[5];   // scalar
  float* out = (float*)d_out;

  // ws layout (every region fully rewritten before use each call)
  double* hPart    = (double*)d_ws;                            // 4 MB
  double* jsegPart = (double*)((char*)d_ws + (4 << 20));       // 2 KB
  float*  zPart    = (float*)((char*)d_ws + (4 << 20) + 8192); // 1 KB
  float*  ctxPart  = (float*)((char*)d_ws + (5 << 20));        // 1 MB

  kA1<<<dim3(32, 16), 256, 0, stream>>>(tgt, Wp, hPart);
  kA2<<<dim3(NB, 16), 64, 0, stream>>>(hPart, bp, vp, jsegPart);
  kB<<<NB * NCHUNK, 512, 0, stream>>>(src, tgt, jsegPart, bv, zPart, ctxPart);
  kC<<<dim3(NB, 16), 256, 0, stream>>>(zPart, ctxPart, out);
}